// Round 14
// baseline (179.977 us; speedup 1.0000x reference)
//
#include <hip/hip_runtime.h>
#include <hip/hip_bf16.h>
#include <math.h>

// Problem constants
#define V_ 5
#define B_ 2
#define C_ 32
#define D_ 48
#define H_ 128
#define W_ 160
#define NSRC 4
#define HW_ (H_ * W_)
#define DHW_ ((size_t)D_ * H_ * W_)
#define BHW_ (B_ * H_ * W_)             // 40960
#define TOTAL_BDHW (B_ * D_ * H_ * W_)  // 1966080

// vol grid geometry: block = 256 thr = (16 w) x (4 c-quarters) x (4 h)
// logical block id: d innermost, then wg (W/16=10), then h4 (H/4=32), then b
#define NB_VOL (B_ * (H_ / 4) * (W_ / 16) * D_)  // 30720
#define NB_VOL8 (NB_VOL / 8)                     // 3840

typedef __attribute__((ext_vector_type(2))) float f32x2;

// ---------------------------------------------------------------------------
// K0: projection setup (8 threads, f64 internally).
// ---------------------------------------------------------------------------
__device__ __forceinline__ void combined_proj(const float* p, double* P) {
    double E[16], K[16];
    for (int i = 0; i < 16; ++i) { E[i] = (double)p[i]; K[i] = (double)p[16 + i]; }
    for (int i = 0; i < 16; ++i) P[i] = E[i];
    for (int r = 0; r < 3; ++r)
        for (int c = 0; c < 4; ++c) {
            double s = 0.0;
            for (int j = 0; j < 3; ++j) s += K[r * 4 + j] * E[j * 4 + c];
            P[r * 4 + c] = s;
        }
}

__device__ void invert4(const double* A, double* out) {
    double M[4][8];
    for (int r = 0; r < 4; ++r)
        for (int c = 0; c < 4; ++c) {
            M[r][c] = A[r * 4 + c];
            M[r][c + 4] = (r == c) ? 1.0 : 0.0;
        }
    for (int col = 0; col < 4; ++col) {
        int piv = col;
        double best = fabs(M[col][col]);
        for (int r = col + 1; r < 4; ++r) {
            double v = fabs(M[r][col]);
            if (v > best) { best = v; piv = r; }
        }
        if (piv != col)
            for (int c = 0; c < 8; ++c) {
                double t = M[col][c]; M[col][c] = M[piv][c]; M[piv][c] = t;
            }
        double s = 1.0 / M[col][col];
        for (int c = 0; c < 8; ++c) M[col][c] *= s;
        for (int r = 0; r < 4; ++r)
            if (r != col) {
                double f = M[r][col];
                if (f != 0.0)
                    for (int c = 0; c < 8; ++c) M[r][c] -= f * M[col][c];
            }
    }
    for (int r = 0; r < 4; ++r)
        for (int c = 0; c < 4; ++c) out[r * 4 + c] = M[r][c + 4];
}

__global__ void proj_kernel(const float* __restrict__ pm, float* __restrict__ out) {
    int t = threadIdx.x;
    if (t >= B_ * NSRC) return;
    int b = t / NSRC, i = t % NSRC;
    double Pref[16], Psrc[16];
    combined_proj(pm + (size_t)((b * V_ + 0) * 2) * 16, Pref);
    combined_proj(pm + (size_t)((b * V_ + (i + 1)) * 2) * 16, Psrc);
    double inv[16];
    invert4(Pref, inv);
    double M[16];
    for (int r = 0; r < 4; ++r)
        for (int c = 0; c < 4; ++c) {
            double s = 0.0;
            for (int j = 0; j < 4; ++j) s += Psrc[r * 4 + j] * inv[j * 4 + c];
            M[r * 4 + c] = s;
        }
    float* o = out + t * 12;
    o[0] = (float)M[0];  o[1] = (float)M[1];  o[2] = (float)M[2];
    o[3] = (float)M[4];  o[4] = (float)M[5];  o[5] = (float)M[6];
    o[6] = (float)M[8];  o[7] = (float)M[9];  o[8] = (float)M[10];
    o[9] = (float)M[3];  o[10] = (float)M[7]; o[11] = (float)M[11];
}

// ---------------------------------------------------------------------------
// K1: transpose ALL 5 views: v=0 (ref) -> channel-last f32 (b, h, w, c);
//     v=1..4 (src) -> channel-last bf16 (i=v-1, b, h, w, c).
// ---------------------------------------------------------------------------
__global__ __launch_bounds__(256) void transpose5_kernel(
    const float* __restrict__ in, __hip_bfloat16* __restrict__ outT,
    float* __restrict__ refT) {
    __shared__ float tile[32][33];
    int vbh = blockIdx.x;                 // (v*B + b)*H + h
    int w0 = blockIdx.y * 32;
    int h = vbh % H_;
    int vb = vbh / H_;                    // v*B + b
    int v = vb / B_, b = vb % B_;
    int tx = threadIdx.x, ty = threadIdx.y;
    const float* src = in + ((size_t)vb * C_) * HW_ + (size_t)h * W_ + w0;
#pragma unroll
    for (int cs = 0; cs < 32; cs += 8)
        tile[cs + ty][tx] = src[(size_t)(cs + ty) * HW_ + tx];
    __syncthreads();
    if (v == 0) {
        float* dst = refT + ((size_t)b * HW_ + (size_t)h * W_ + w0) * C_;
#pragma unroll
        for (int wv = 0; wv < 32; wv += 8)
            dst[(size_t)(wv + ty) * C_ + tx] = tile[tx][wv + ty];
    } else {
        __hip_bfloat16* dst = outT +
            ((size_t)((v - 1) * B_ + b) * HW_ + (size_t)h * W_ + w0) * C_;
#pragma unroll
        for (int wv = 0; wv < 32; wv += 8)
            dst[(size_t)(wv + ty) * C_ + tx] = __float2bfloat16(tile[tx][wv + ty]);
    }
}

// ---------------------------------------------------------------------------
// K1b: pack view_weights (B,4,H,W) -> (B,H,W,4) float4.
// ---------------------------------------------------------------------------
__global__ __launch_bounds__(256) void vwpack_kernel(
    const float* __restrict__ vw, float4* __restrict__ vwp) {
    int tid = blockIdx.x * 256 + threadIdx.x;
    if (tid >= BHW_) return;
    int hw = tid % HW_;
    int b = tid / HW_;
    float4 o;
    o.x = vw[((size_t)(b * NSRC + 0)) * HW_ + hw];
    o.y = vw[((size_t)(b * NSRC + 1)) * HW_ + hw];
    o.z = vw[((size_t)(b * NSRC + 2)) * HW_ + hw];
    o.w = vw[((size_t)(b * NSRC + 3)) * HW_ + hw];
    vwp[(size_t)b * HW_ + hw] = o;
}

// ---------------------------------------------------------------------------
// K2 (full path): r13 kernel with vmem-instruction cuts:
//   - ref view: 2x dwordx4 from f32 channel-last refT (was 8 strided dwords)
//   - view_weights: 1x dwordx4 from packed vwp (was 4 strided dwords)
// 40 -> ~31 vmem instrs/thread; TA/address-processing bound attack.
// Everything else identical (bf16 gathers, d-innermost + XCD swizzle, rcp,
// pk_fma accumulate, NT stores).
// ---------------------------------------------------------------------------
__global__ __launch_bounds__(256) void vol_bf16p_kernel(
    const __hip_bfloat16* __restrict__ featT, const float* __restrict__ refT,
    const float4* __restrict__ vwp, const float* __restrict__ depth_samples,
    const float* __restrict__ w_reg, const float* __restrict__ b_reg,
    const float* __restrict__ projs, float* __restrict__ out_vol,
    float* __restrict__ out_pv) {
    int bid = blockIdx.x;
    int lid = (bid & 7) * NB_VOL8 + (bid >> 3);   // bijective XCD chunking
    int d = lid % D_;
    int r = lid / D_;
    int wg = r % (W_ / 16);
    r /= (W_ / 16);
    int h4 = r % (H_ / 4);
    int b = r / (H_ / 4);                          // block-uniform -> SGPR

    int tix = threadIdx.x;
    int w16 = tix & 15;
    int c4 = (tix >> 4) & 3;
    int hg = tix >> 6;
    int h = h4 * 4 + hg;
    int w = wg * 16 + w16;
    int c0 = c4 * 8;

    int pix_idx = ((b * D_ + d) * H_ + h) * W_ + w;
    int hw = h * W_ + w;
    float xf = (float)w, yf = (float)h;
    float dep = depth_samples[pix_idx];
    float4 vw4 = vwp[(size_t)b * HW_ + hw];        // one dwordx4
    float vwa[4] = {vw4.x, vw4.y, vw4.z, vw4.w};
    float wsum = 1e-5f + vw4.x + vw4.y + vw4.z + vw4.w;

    f32x2 acc[4];
#pragma unroll
    for (int j = 0; j < 4; ++j) acc[j] = (f32x2){0.f, 0.f};

#pragma unroll
    for (int i = 0; i < NSRC; ++i) {
        float vw = vwa[i];
        const float* pr = projs + (b * NSRC + i) * 12;   // uniform -> s_load
        float rx = pr[0] * xf + pr[1] * yf + pr[2];
        float ry = pr[3] * xf + pr[4] * yf + pr[5];
        float rz = pr[6] * xf + pr[7] * yf + pr[8];
        float pxn = rx * dep + pr[9];
        float pyn = ry * dep + pr[10];
        float z = rz * dep + pr[11];
        bool valid = z > 0.001f;
        float zr = __builtin_amdgcn_rcpf(valid ? z : 1.f);
        float px = valid ? pxn * zr : -10000.f;
        float py = valid ? pyn * zr : -10000.f;

        float x0f = floorf(px), y0f = floorf(py);
        float x1f = x0f + 1.f, y1f = y0f + 1.f;
        float wx1 = px - x0f, wx0 = 1.f - wx1;
        float wy1 = py - y0f, wy0 = 1.f - wy1;
        bool vx0 = (x0f >= 0.f) && (x0f <= (float)(W_ - 1));
        bool vx1 = (x1f >= 0.f) && (x1f <= (float)(W_ - 1));
        bool vy0 = (y0f >= 0.f) && (y0f <= (float)(H_ - 1));
        bool vy1 = (y1f >= 0.f) && (y1f <= (float)(H_ - 1));
        int ix0 = (int)fminf(fmaxf(x0f, 0.f), (float)(W_ - 1));
        int ix1 = (int)fminf(fmaxf(x1f, 0.f), (float)(W_ - 1));
        int iy0 = (int)fminf(fmaxf(y0f, 0.f), (float)(H_ - 1));
        int iy1 = (int)fminf(fmaxf(y1f, 0.f), (float)(H_ - 1));
        float w00 = wx0 * wy0 * ((vx0 && vy0) ? vw : 0.f);
        float w10 = wx1 * wy0 * ((vx1 && vy0) ? vw : 0.f);
        float w01 = wx0 * wy1 * ((vx0 && vy1) ? vw : 0.f);
        float w11 = wx1 * wy1 * ((vx1 && vy1) ? vw : 0.f);

        const __hip_bfloat16* base = featT + (size_t)(i * B_ + b) * HW_ * C_ + c0;
        uint4 u00 = *(const uint4*)(base + (size_t)(iy0 * W_ + ix0) * C_);
        uint4 u10 = *(const uint4*)(base + (size_t)(iy0 * W_ + ix1) * C_);
        uint4 u01 = *(const uint4*)(base + (size_t)(iy1 * W_ + ix0) * C_);
        uint4 u11 = *(const uint4*)(base + (size_t)(iy1 * W_ + ix1) * C_);

#define ACCPK(word, j, wv2)                                              \
        {                                                                \
            f32x2 tt;                                                    \
            tt.x = __uint_as_float((word) << 16);                        \
            tt.y = __uint_as_float((word) & 0xffff0000u);                \
            acc[j] += tt * (wv2);                                        \
        }
#define ACCTAP(uu, wgt)                                                  \
        {                                                                \
            f32x2 wv2 = (f32x2){(wgt), (wgt)};                           \
            ACCPK((uu).x, 0, wv2)                                        \
            ACCPK((uu).y, 1, wv2)                                        \
            ACCPK((uu).z, 2, wv2)                                        \
            ACCPK((uu).w, 3, wv2)                                        \
        }
        ACCTAP(u00, w00)
        ACCTAP(u10, w10)
        ACCTAP(u01, w01)
        ACCTAP(u11, w11)
#undef ACCTAP
#undef ACCPK
    }

    float inv_wsum = __builtin_amdgcn_rcpf(wsum);   // wsum in [0.4, 4.0001]
    size_t obase = (size_t)b * C_ * DHW_ + (size_t)d * HW_ + hw;
    // ref view: f32 channel-last -> two dwordx4
    const float4* rp = (const float4*)(refT + ((size_t)b * HW_ + hw) * C_ + c0);
    float4 r0 = rp[0], r1 = rp[1];
    f32x2 iw2 = (f32x2){inv_wsum, inv_wsum};
    f32x2 vc2[4];
    vc2[0] = (f32x2){r0.x, r0.y} * acc[0] * iw2;
    vc2[1] = (f32x2){r0.z, r0.w} * acc[1] * iw2;
    vc2[2] = (f32x2){r1.x, r1.y} * acc[2] * iw2;
    vc2[3] = (f32x2){r1.z, r1.w} * acc[3] * iw2;
    float pv = 0.f;
#pragma unroll
    for (int k = 0; k < 8; ++k) {
        float vc = vc2[k >> 1][k & 1];
        __builtin_nontemporal_store(vc, &out_vol[obase + (size_t)(c0 + k) * DHW_]);
        pv += vc * w_reg[c0 + k];
    }
    pv += __shfl_xor(pv, 16, 64);
    pv += __shfl_xor(pv, 32, 64);
    if (c4 == 0) out_pv[pix_idx] = pv + b_reg[0];
}

// ---------------------------------------------------------------------------
// K2 (tier1 path): exact r13 kernel (proven 159 µs) — used if ws too small.
// ---------------------------------------------------------------------------
__global__ __launch_bounds__(256) void vol_bf16_kernel(
    const __hip_bfloat16* __restrict__ featT, const float* __restrict__ features,
    const float* __restrict__ depth_samples, const float* __restrict__ view_weights,
    const float* __restrict__ w_reg, const float* __restrict__ b_reg,
    const float* __restrict__ projs, float* __restrict__ out_vol,
    float* __restrict__ out_pv) {
    int bid = blockIdx.x;
    int lid = (bid & 7) * NB_VOL8 + (bid >> 3);
    int d = lid % D_;
    int r = lid / D_;
    int wg = r % (W_ / 16);
    r /= (W_ / 16);
    int h4 = r % (H_ / 4);
    int b = r / (H_ / 4);

    int tix = threadIdx.x;
    int w16 = tix & 15;
    int c4 = (tix >> 4) & 3;
    int hg = tix >> 6;
    int h = h4 * 4 + hg;
    int w = wg * 16 + w16;
    int c0 = c4 * 8;

    int pix_idx = ((b * D_ + d) * H_ + h) * W_ + w;
    float xf = (float)w, yf = (float)h;
    float dep = depth_samples[pix_idx];

    f32x2 acc[4];
#pragma unroll
    for (int j = 0; j < 4; ++j) acc[j] = (f32x2){0.f, 0.f};
    float wsum = 1e-5f;

#pragma unroll
    for (int i = 0; i < NSRC; ++i) {
        float vw = view_weights[((size_t)(b * NSRC + i) * H_ + h) * W_ + w];
        wsum += vw;
        const float* pr = projs + (b * NSRC + i) * 12;
        float rx = pr[0] * xf + pr[1] * yf + pr[2];
        float ry = pr[3] * xf + pr[4] * yf + pr[5];
        float rz = pr[6] * xf + pr[7] * yf + pr[8];
        float pxn = rx * dep + pr[9];
        float pyn = ry * dep + pr[10];
        float z = rz * dep + pr[11];
        bool valid = z > 0.001f;
        float zr = __builtin_amdgcn_rcpf(valid ? z : 1.f);
        float px = valid ? pxn * zr : -10000.f;
        float py = valid ? pyn * zr : -10000.f;

        float x0f = floorf(px), y0f = floorf(py);
        float x1f = x0f + 1.f, y1f = y0f + 1.f;
        float wx1 = px - x0f, wx0 = 1.f - wx1;
        float wy1 = py - y0f, wy0 = 1.f - wy1;
        bool vx0 = (x0f >= 0.f) && (x0f <= (float)(W_ - 1));
        bool vx1 = (x1f >= 0.f) && (x1f <= (float)(W_ - 1));
        bool vy0 = (y0f >= 0.f) && (y0f <= (float)(H_ - 1));
        bool vy1 = (y1f >= 0.f) && (y1f <= (float)(H_ - 1));
        int ix0 = (int)fminf(fmaxf(x0f, 0.f), (float)(W_ - 1));
        int ix1 = (int)fminf(fmaxf(x1f, 0.f), (float)(W_ - 1));
        int iy0 = (int)fminf(fmaxf(y0f, 0.f), (float)(H_ - 1));
        int iy1 = (int)fminf(fmaxf(y1f, 0.f), (float)(H_ - 1));
        float w00 = wx0 * wy0 * ((vx0 && vy0) ? vw : 0.f);
        float w10 = wx1 * wy0 * ((vx1 && vy0) ? vw : 0.f);
        float w01 = wx0 * wy1 * ((vx0 && vy1) ? vw : 0.f);
        float w11 = wx1 * wy1 * ((vx1 && vy1) ? vw : 0.f);

        const __hip_bfloat16* base = featT + (size_t)(i * B_ + b) * HW_ * C_ + c0;
        uint4 u00 = *(const uint4*)(base + (size_t)(iy0 * W_ + ix0) * C_);
        uint4 u10 = *(const uint4*)(base + (size_t)(iy0 * W_ + ix1) * C_);
        uint4 u01 = *(const uint4*)(base + (size_t)(iy1 * W_ + ix0) * C_);
        uint4 u11 = *(const uint4*)(base + (size_t)(iy1 * W_ + ix1) * C_);

#define ACCPK(word, j, wv2)                                              \
        {                                                                \
            f32x2 tt;                                                    \
            tt.x = __uint_as_float((word) << 16);                        \
            tt.y = __uint_as_float((word) & 0xffff0000u);                \
            acc[j] += tt * (wv2);                                        \
        }
#define ACCTAP(uu, wgt)                                                  \
        {                                                                \
            f32x2 wv2 = (f32x2){(wgt), (wgt)};                           \
            ACCPK((uu).x, 0, wv2)                                        \
            ACCPK((uu).y, 1, wv2)                                        \
            ACCPK((uu).z, 2, wv2)                                        \
            ACCPK((uu).w, 3, wv2)                                        \
        }
        ACCTAP(u00, w00)
        ACCTAP(u10, w10)
        ACCTAP(u01, w01)
        ACCTAP(u11, w11)
#undef ACCTAP
#undef ACCPK
    }

    float inv_wsum = __builtin_amdgcn_rcpf(wsum);
    size_t obase = (size_t)b * C_ * DHW_ + (size_t)d * HW_ + (size_t)h * W_ + w;
    const float* refp = features + ((size_t)b * C_ + c0) * HW_ + (size_t)h * W_ + w;
    f32x2 iw2 = (f32x2){inv_wsum, inv_wsum};
    f32x2 vc2[4];
#pragma unroll
    for (int j = 0; j < 4; ++j) {
        f32x2 rf;
        rf.x = refp[(size_t)(2 * j) * HW_];
        rf.y = refp[(size_t)(2 * j + 1) * HW_];
        vc2[j] = rf * acc[j] * iw2;
    }
    float pv = 0.f;
#pragma unroll
    for (int k = 0; k < 8; ++k) {
        float vc = vc2[k >> 1][k & 1];
        __builtin_nontemporal_store(vc, &out_vol[obase + (size_t)(c0 + k) * DHW_]);
        pv += vc * w_reg[c0 + k];
    }
    pv += __shfl_xor(pv, 16, 64);
    pv += __shfl_xor(pv, 32, 64);
    if (c4 == 0) out_pv[pix_idx] = pv + b_reg[0];
}

// ---------------------------------------------------------------------------
// Fallback: one-thread-per-pixel channel-first f32 kernel (no workspace).
// ---------------------------------------------------------------------------
__global__ __launch_bounds__(256) void vol_fallback_kernel(
    const float* __restrict__ feat, const float* __restrict__ depth_samples,
    const float* __restrict__ view_weights, const float* __restrict__ w_reg,
    const float* __restrict__ b_reg, const float* __restrict__ projs,
    float* __restrict__ out_vol, float* __restrict__ out_pv) {
    int tid = blockIdx.x * 256 + threadIdx.x;
    if (tid >= TOTAL_BDHW) return;
    int w = tid % W_;
    int t2 = tid / W_;
    int h = t2 % H_;
    t2 /= H_;
    int d = t2 % D_;
    int b = t2 / D_;

    float xf = (float)w, yf = (float)h;
    float dep = depth_samples[tid];
    float s[C_];
#pragma unroll
    for (int c = 0; c < C_; ++c) s[c] = 0.f;
    float wsum = 1e-5f;

    for (int i = 0; i < NSRC; ++i) {
        float vw = view_weights[((size_t)(b * NSRC + i) * H_ + h) * W_ + w];
        wsum += vw;
        const float* pr = projs + (b * NSRC + i) * 12;
        float rx = pr[0] * xf + pr[1] * yf + pr[2];
        float ry = pr[3] * xf + pr[4] * yf + pr[5];
        float rz = pr[6] * xf + pr[7] * yf + pr[8];
        float pxn = rx * dep + pr[9];
        float pyn = ry * dep + pr[10];
        float z = rz * dep + pr[11];
        bool valid = z > 0.001f;
        float zs = valid ? z : 1.f;
        float px = valid ? pxn / zs : -10000.f;
        float py = valid ? pyn / zs : -10000.f;
        float x0f = floorf(px), y0f = floorf(py);
        float x1f = x0f + 1.f, y1f = y0f + 1.f;
        float wx1 = px - x0f, wx0 = 1.f - wx1;
        float wy1 = py - y0f, wy0 = 1.f - wy1;
        bool vx0 = (x0f >= 0.f) && (x0f <= (float)(W_ - 1));
        bool vx1 = (x1f >= 0.f) && (x1f <= (float)(W_ - 1));
        bool vy0 = (y0f >= 0.f) && (y0f <= (float)(H_ - 1));
        bool vy1 = (y1f >= 0.f) && (y1f <= (float)(H_ - 1));
        int ix0 = (int)fminf(fmaxf(x0f, 0.f), (float)(W_ - 1));
        int ix1 = (int)fminf(fmaxf(x1f, 0.f), (float)(W_ - 1));
        int iy0 = (int)fminf(fmaxf(y0f, 0.f), (float)(H_ - 1));
        int iy1 = (int)fminf(fmaxf(y1f, 0.f), (float)(H_ - 1));
        float w00 = wx0 * wy0 * ((vx0 && vy0) ? vw : 0.f);
        float w10 = wx1 * wy0 * ((vx1 && vy0) ? vw : 0.f);
        float w01 = wx0 * wy1 * ((vx0 && vy1) ? vw : 0.f);
        float w11 = wx1 * wy1 * ((vx1 && vy1) ? vw : 0.f);
        const float* base = feat + (size_t)((i + 1) * B_ + b) * C_ * HW_;
        const float* q00 = base + (size_t)iy0 * W_ + ix0;
        const float* q10 = base + (size_t)iy0 * W_ + ix1;
        const float* q01 = base + (size_t)iy1 * W_ + ix0;
        const float* q11 = base + (size_t)iy1 * W_ + ix1;
#pragma unroll
        for (int c = 0; c < C_; ++c)
            s[c] += q00[(size_t)c * HW_] * w00 + q10[(size_t)c * HW_] * w10 +
                    q01[(size_t)c * HW_] * w01 + q11[(size_t)c * HW_] * w11;
    }
    float inv_wsum = 1.f / wsum;
    size_t obase = (size_t)b * C_ * DHW_ + (size_t)d * HW_ + (size_t)h * W_ + w;
    const float* refp = feat + (size_t)b * C_ * HW_ + (size_t)h * W_ + w;
    float pv = 0.f;
#pragma unroll
    for (int c = 0; c < C_; ++c) {
        float vc = refp[(size_t)c * HW_] * s[c] * inv_wsum;
        out_vol[obase + (size_t)c * DHW_] = vc;
        pv += vc * w_reg[c];
    }
    out_pv[tid] = pv + b_reg[0];
}

// ---------------------------------------------------------------------------
// K3: softmax over D (in-place on pv = prob slot), depth, vw passthrough.
// ---------------------------------------------------------------------------
__global__ __launch_bounds__(256) void finalize_kernel(
    const float* __restrict__ ds, const float* __restrict__ vw,
    float* __restrict__ out_depth, float* __restrict__ out_vw,
    float* __restrict__ pv) {
    int tid = blockIdx.x * 256 + threadIdx.x;
    if (tid >= BHW_) return;
    int w = tid % W_;
    int t2 = tid / W_;
    int h = t2 % H_;
    int b = t2 / H_;
    size_t base = (size_t)b * DHW_ + (size_t)h * W_ + w;

    float p[D_];
    float m = -1e30f;
#pragma unroll
    for (int d = 0; d < D_; ++d) {
        p[d] = pv[base + (size_t)d * HW_];
        m = fmaxf(m, p[d]);
    }
    float ssum = 0.f;
#pragma unroll
    for (int d = 0; d < D_; ++d) {
        p[d] = expf(p[d] - m);
        ssum += p[d];
    }
    float inv = 1.f / ssum;
    float dep = 0.f;
#pragma unroll
    for (int d = 0; d < D_; ++d) {
        float pr = p[d] * inv;
        pv[base + (size_t)d * HW_] = pr;
        dep += pr * ds[base + (size_t)d * HW_];
    }
    out_depth[tid] = dep;
#pragma unroll
    for (int k = 0; k < NSRC; ++k)
        out_vw[tid + k * BHW_] = vw[tid + k * BHW_];
}

// ---------------------------------------------------------------------------
extern "C" void kernel_launch(void* const* d_in, const int* in_sizes, int n_in,
                              void* d_out, int out_size, void* d_ws, size_t ws_size,
                              hipStream_t stream) {
    const float* features = (const float*)d_in[0];
    const float* pm       = (const float*)d_in[1];
    const float* dsamp    = (const float*)d_in[2];
    const float* vweights = (const float*)d_in[3];
    const float* w_reg    = (const float*)d_in[4];
    const float* b_reg    = (const float*)d_in[5];

    float* out = (float*)d_out;
    float* out_depth = out;                       // (B,H,W)      40960
    float* out_vw    = out + 40960;               // (B,4,H,W)    163840
    float* out_prob  = out + 204800;              // (B,D,H,W)    1966080 (pv staged here)
    float* out_vol   = out + 2170880;             // (B,C,D,H,W)  62914560

    char* wsb = (char*)d_ws;
    float* projb = (float*)wsb;                               // 512 B
    size_t featT_bytes = (size_t)NSRC * B_ * HW_ * C_ * 2;    // 10485760
    size_t refT_bytes  = (size_t)B_ * HW_ * C_ * 4;           // 5242880
    size_t vwp_bytes   = (size_t)BHW_ * 16;                   // 655360
    __hip_bfloat16* featT = (__hip_bfloat16*)(wsb + 512);
    float* refT = (float*)(wsb + 512 + featT_bytes);
    float4* vwp = (float4*)(wsb + 512 + featT_bytes + refT_bytes);

    size_t need_full  = 512 + featT_bytes + refT_bytes + vwp_bytes;  // ~16.4 MB
    size_t need_tier1 = 512 + featT_bytes;                           // ~10.5 MB

    hipLaunchKernelGGL(proj_kernel, dim3(1), dim3(64), 0, stream, pm, projb);

    if (ws_size >= need_full) {
        hipLaunchKernelGGL(transpose5_kernel, dim3(V_ * B_ * H_, W_ / 32),
                           dim3(32, 8), 0, stream, features, featT, refT);
        hipLaunchKernelGGL(vwpack_kernel, dim3(BHW_ / 256), dim3(256), 0, stream,
                           vweights, vwp);
        hipLaunchKernelGGL(vol_bf16p_kernel, dim3(NB_VOL), dim3(256), 0, stream,
                           featT, refT, vwp, dsamp, w_reg, b_reg, projb,
                           out_vol, out_prob);
    } else if (ws_size >= need_tier1) {
        // r13 path: src transpose only (reuse transpose5 grid for v=1..4 by
        // launching the full kernel is not possible without refT; use a
        // dedicated pass writing only bf16 views via the same kernel would
        // need refT — instead fall back to the proven per-view kernel.
        hipLaunchKernelGGL(transpose5_kernel, dim3(V_ * B_ * H_, W_ / 32),
                           dim3(32, 8), 0, stream, features, featT,
                           (float*)featT /*unused v=0 writes overwritten? no —
                           v=0 writes f32 into featT region; avoid by tier*/);
        // NOTE: tier1 uses the r13 kernel reading ref from original features;
        // the v=0 f32 writes above land in featT's first view slot — WRONG.
        // To stay safe, tier1 instead re-runs the full-src transpose below.
        hipLaunchKernelGGL(vol_fallback_kernel, dim3((TOTAL_BDHW + 255) / 256),
                           dim3(256), 0, stream, features, dsamp, vweights,
                           w_reg, b_reg, projb, out_vol, out_prob);
    } else {
        hipLaunchKernelGGL(vol_fallback_kernel, dim3((TOTAL_BDHW + 255) / 256),
                           dim3(256), 0, stream, features, dsamp, vweights,
                           w_reg, b_reg, projb, out_vol, out_prob);
    }

    hipLaunchKernelGGL(finalize_kernel, dim3(BHW_ / 256), dim3(256), 0, stream,
                       dsamp, vweights, out_depth, out_vw, out_prob);
}

// Round 15
// 151.174 us; speedup vs baseline: 1.1905x; 1.1905x over previous
//
#include <hip/hip_runtime.h>
#include <hip/hip_bf16.h>
#include <math.h>

// Problem constants
#define V_ 5
#define B_ 2
#define C_ 32
#define D_ 48
#define H_ 128
#define W_ 160
#define NSRC 4
#define HW_ (H_ * W_)
#define DHW_ ((size_t)D_ * H_ * W_)
#define BHW_ (B_ * H_ * W_)             // 40960
#define TOTAL_BDHW (B_ * D_ * H_ * W_)  // 1966080

// d-pair grid: block = 256 thr = (16 w) x (4 c-quarters) x (4 h), TWO d each.
// logical block id: dp innermost, then wg (10), h4 (32), b.
#define DPAIR (D_ / 2)                                // 24
#define NB_PAIR (B_ * (H_ / 4) * (W_ / 16) * DPAIR)   // 15360
#define NB_PAIR8 (NB_PAIR / 8)                        // 1920

typedef __attribute__((ext_vector_type(2))) float f32x2;

// ---------------------------------------------------------------------------
// K0: projection setup (8 threads, f64 internally).
// ---------------------------------------------------------------------------
__device__ __forceinline__ void combined_proj(const float* p, double* P) {
    double E[16], K[16];
    for (int i = 0; i < 16; ++i) { E[i] = (double)p[i]; K[i] = (double)p[16 + i]; }
    for (int i = 0; i < 16; ++i) P[i] = E[i];
    for (int r = 0; r < 3; ++r)
        for (int c = 0; c < 4; ++c) {
            double s = 0.0;
            for (int j = 0; j < 3; ++j) s += K[r * 4 + j] * E[j * 4 + c];
            P[r * 4 + c] = s;
        }
}

__device__ void invert4(const double* A, double* out) {
    double M[4][8];
    for (int r = 0; r < 4; ++r)
        for (int c = 0; c < 4; ++c) {
            M[r][c] = A[r * 4 + c];
            M[r][c + 4] = (r == c) ? 1.0 : 0.0;
        }
    for (int col = 0; col < 4; ++col) {
        int piv = col;
        double best = fabs(M[col][col]);
        for (int r = col + 1; r < 4; ++r) {
            double v = fabs(M[r][col]);
            if (v > best) { best = v; piv = r; }
        }
        if (piv != col)
            for (int c = 0; c < 8; ++c) {
                double t = M[col][c]; M[col][c] = M[piv][c]; M[piv][c] = t;
            }
        double s = 1.0 / M[col][col];
        for (int c = 0; c < 8; ++c) M[col][c] *= s;
        for (int r = 0; r < 4; ++r)
            if (r != col) {
                double f = M[r][col];
                if (f != 0.0)
                    for (int c = 0; c < 8; ++c) M[r][c] -= f * M[col][c];
            }
    }
    for (int r = 0; r < 4; ++r)
        for (int c = 0; c < 4; ++c) out[r * 4 + c] = M[r][c + 4];
}

__global__ void proj_kernel(const float* __restrict__ pm, float* __restrict__ out) {
    int t = threadIdx.x;
    if (t >= B_ * NSRC) return;
    int b = t / NSRC, i = t % NSRC;
    double Pref[16], Psrc[16];
    combined_proj(pm + (size_t)((b * V_ + 0) * 2) * 16, Pref);
    combined_proj(pm + (size_t)((b * V_ + (i + 1)) * 2) * 16, Psrc);
    double inv[16];
    invert4(Pref, inv);
    double M[16];
    for (int r = 0; r < 4; ++r)
        for (int c = 0; c < 4; ++c) {
            double s = 0.0;
            for (int j = 0; j < 4; ++j) s += Psrc[r * 4 + j] * inv[j * 4 + c];
            M[r * 4 + c] = s;
        }
    float* o = out + t * 12;
    o[0] = (float)M[0];  o[1] = (float)M[1];  o[2] = (float)M[2];
    o[3] = (float)M[4];  o[4] = (float)M[5];  o[5] = (float)M[6];
    o[6] = (float)M[8];  o[7] = (float)M[9];  o[8] = (float)M[10];
    o[9] = (float)M[3];  o[10] = (float)M[7]; o[11] = (float)M[11];
}

// ---------------------------------------------------------------------------
// K1: transpose + convert src views: (v=1..4, b, c, h, w) f32
//     -> channel-last bf16 (i, b, h, w, c), i = v-1.
// ---------------------------------------------------------------------------
__global__ __launch_bounds__(256) void transpose_bf16_kernel(
    const float* __restrict__ in, __hip_bfloat16* __restrict__ outT) {
    __shared__ float tile[32][33];
    int ibh = blockIdx.x;                 // (i*B + b)*H + h
    int w0 = blockIdx.y * 32;
    int h = ibh % H_;
    int ib = ibh / H_;                    // i*B + b
    int i = ib / B_, b = ib % B_;
    int tx = threadIdx.x, ty = threadIdx.y;
    const float* src = in + ((size_t)((i + 1) * B_ + b) * C_) * HW_ + (size_t)h * W_ + w0;
#pragma unroll
    for (int cs = 0; cs < 32; cs += 8)
        tile[cs + ty][tx] = src[(size_t)(cs + ty) * HW_ + tx];
    __syncthreads();
    __hip_bfloat16* dst = outT + ((size_t)ib * HW_ + (size_t)h * W_ + w0) * C_;
#pragma unroll
    for (int wv = 0; wv < 32; wv += 8)
        dst[(size_t)(wv + ty) * C_ + tx] = __float2bfloat16(tile[tx][wv + ty]);
}

// ---------------------------------------------------------------------------
// K2: sequential d-pair volume kernel (discriminating experiment).
// Exact r13 per-d body, wrapped in dd in {0,1}: d1's gathers hit lines d0
// just pulled into THIS CU's L1 (~75% overlap). d-invariant state (vw,
// wsum, ref, w_reg, per-view rx/ry/rz) hoisted out of the dd loop.
// No LDS, no barriers, no sched pinning.
// ---------------------------------------------------------------------------
__global__ __launch_bounds__(256) void vol_pair_kernel(
    const __hip_bfloat16* __restrict__ featT, const float* __restrict__ features,
    const float* __restrict__ depth_samples, const float* __restrict__ view_weights,
    const float* __restrict__ w_reg, const float* __restrict__ b_reg,
    const float* __restrict__ projs, float* __restrict__ out_vol,
    float* __restrict__ out_pv) {
    int bid = blockIdx.x;
    int lid = (bid & 7) * NB_PAIR8 + (bid >> 3);   // bijective XCD chunking
    int dp = lid % DPAIR;
    int r = lid / DPAIR;
    int wg = r % (W_ / 16);
    r /= (W_ / 16);
    int h4 = r % (H_ / 4);
    int b = r / (H_ / 4);                          // block-uniform -> SGPR
    int d0 = dp * 2;

    int tix = threadIdx.x;
    int w16 = tix & 15;
    int c4 = (tix >> 4) & 3;
    int hg = tix >> 6;
    int h = h4 * 4 + hg;
    int w = wg * 16 + w16;
    int c0 = c4 * 8;
    int hw = h * W_ + w;
    float xf = (float)w, yf = (float)h;

    // ---- d-invariant state ----
    float vwa[NSRC];
    float wsum = 1e-5f;
#pragma unroll
    for (int i = 0; i < NSRC; ++i) {
        vwa[i] = view_weights[((size_t)(b * NSRC + i)) * HW_ + hw];
        wsum += vwa[i];
    }
    float inv_wsum = __builtin_amdgcn_rcpf(wsum);   // wsum in [0.4, 4.0001]
    f32x2 iw2 = (f32x2){inv_wsum, inv_wsum};

    const float* refp = features + ((size_t)b * C_ + c0) * HW_ + hw;
    f32x2 rf2[4];
#pragma unroll
    for (int j = 0; j < 4; ++j) {
        rf2[j].x = refp[(size_t)(2 * j) * HW_];
        rf2[j].y = refp[(size_t)(2 * j + 1) * HW_];
    }
    float wrr[8];
#pragma unroll
    for (int k = 0; k < 8; ++k) wrr[k] = w_reg[c0 + k];
    float breg = b_reg[0];

    // per-view projection pieces (depend on (w,h) only)
    float rxv[NSRC], ryv[NSRC], rzv[NSRC];
#pragma unroll
    for (int i = 0; i < NSRC; ++i) {
        const float* pr = projs + (b * NSRC + i) * 12;
        rxv[i] = pr[0] * xf + pr[1] * yf + pr[2];
        ryv[i] = pr[3] * xf + pr[4] * yf + pr[5];
        rzv[i] = pr[6] * xf + pr[7] * yf + pr[8];
    }

    int pixbase = (b * D_) * HW_ + hw;             // + d*HW_
    size_t obase0 = (size_t)b * C_ * DHW_ + hw;    // + d*HW_ + c*DHW_

#pragma unroll
    for (int dd = 0; dd < 2; ++dd) {
        int d = d0 + dd;
        float dep = depth_samples[pixbase + d * HW_];

        f32x2 acc[4];
#pragma unroll
        for (int j = 0; j < 4; ++j) acc[j] = (f32x2){0.f, 0.f};

#pragma unroll
        for (int i = 0; i < NSRC; ++i) {
            float vw = vwa[i];
            const float* pr = projs + (b * NSRC + i) * 12;
            float pxn = rxv[i] * dep + pr[9];
            float pyn = ryv[i] * dep + pr[10];
            float z = rzv[i] * dep + pr[11];
            bool valid = z > 0.001f;
            float zr = __builtin_amdgcn_rcpf(valid ? z : 1.f);
            float px = valid ? pxn * zr : -10000.f;
            float py = valid ? pyn * zr : -10000.f;

            float x0f = floorf(px), y0f = floorf(py);
            float x1f = x0f + 1.f, y1f = y0f + 1.f;
            float wx1 = px - x0f, wx0 = 1.f - wx1;
            float wy1 = py - y0f, wy0 = 1.f - wy1;
            bool vx0 = (x0f >= 0.f) && (x0f <= (float)(W_ - 1));
            bool vx1 = (x1f >= 0.f) && (x1f <= (float)(W_ - 1));
            bool vy0 = (y0f >= 0.f) && (y0f <= (float)(H_ - 1));
            bool vy1 = (y1f >= 0.f) && (y1f <= (float)(H_ - 1));
            int ix0 = (int)fminf(fmaxf(x0f, 0.f), (float)(W_ - 1));
            int ix1 = (int)fminf(fmaxf(x1f, 0.f), (float)(W_ - 1));
            int iy0 = (int)fminf(fmaxf(y0f, 0.f), (float)(H_ - 1));
            int iy1 = (int)fminf(fmaxf(y1f, 0.f), (float)(H_ - 1));
            float w00 = wx0 * wy0 * ((vx0 && vy0) ? vw : 0.f);
            float w10 = wx1 * wy0 * ((vx1 && vy0) ? vw : 0.f);
            float w01 = wx0 * wy1 * ((vx0 && vy1) ? vw : 0.f);
            float w11 = wx1 * wy1 * ((vx1 && vy1) ? vw : 0.f);

            const __hip_bfloat16* base = featT + (size_t)(i * B_ + b) * HW_ * C_ + c0;
            uint4 u00 = *(const uint4*)(base + (size_t)(iy0 * W_ + ix0) * C_);
            uint4 u10 = *(const uint4*)(base + (size_t)(iy0 * W_ + ix1) * C_);
            uint4 u01 = *(const uint4*)(base + (size_t)(iy1 * W_ + ix0) * C_);
            uint4 u11 = *(const uint4*)(base + (size_t)(iy1 * W_ + ix1) * C_);

#define ACCPK(word, j, wv2)                                              \
            {                                                            \
                f32x2 tt;                                                \
                tt.x = __uint_as_float((word) << 16);                    \
                tt.y = __uint_as_float((word) & 0xffff0000u);            \
                acc[j] += tt * (wv2);                                    \
            }
#define ACCTAP(uu, wgt)                                                  \
            {                                                            \
                f32x2 wv2 = (f32x2){(wgt), (wgt)};                       \
                ACCPK((uu).x, 0, wv2)                                    \
                ACCPK((uu).y, 1, wv2)                                    \
                ACCPK((uu).z, 2, wv2)                                    \
                ACCPK((uu).w, 3, wv2)                                    \
            }
            ACCTAP(u00, w00)
            ACCTAP(u10, w10)
            ACCTAP(u01, w01)
            ACCTAP(u11, w11)
#undef ACCTAP
#undef ACCPK
        }

        size_t obase = obase0 + (size_t)d * HW_;
        f32x2 vc2[4];
#pragma unroll
        for (int j = 0; j < 4; ++j) vc2[j] = rf2[j] * acc[j] * iw2;
        float pv = 0.f;
#pragma unroll
        for (int k = 0; k < 8; ++k) {
            float vc = vc2[k >> 1][k & 1];
            __builtin_nontemporal_store(vc, &out_vol[obase + (size_t)(c0 + k) * DHW_]);
            pv += vc * wrr[k];
        }
        pv += __shfl_xor(pv, 16, 64);
        pv += __shfl_xor(pv, 32, 64);
        if (c4 == 0) out_pv[pixbase + d * HW_] = pv + breg;
    }
}

// ---------------------------------------------------------------------------
// Fallback: one-thread-per-pixel channel-first f32 kernel (no workspace).
// ---------------------------------------------------------------------------
__global__ __launch_bounds__(256) void vol_fallback_kernel(
    const float* __restrict__ feat, const float* __restrict__ depth_samples,
    const float* __restrict__ view_weights, const float* __restrict__ w_reg,
    const float* __restrict__ b_reg, const float* __restrict__ projs,
    float* __restrict__ out_vol, float* __restrict__ out_pv) {
    int tid = blockIdx.x * 256 + threadIdx.x;
    if (tid >= TOTAL_BDHW) return;
    int w = tid % W_;
    int t2 = tid / W_;
    int h = t2 % H_;
    t2 /= H_;
    int d = t2 % D_;
    int b = t2 / D_;

    float xf = (float)w, yf = (float)h;
    float dep = depth_samples[tid];
    float s[C_];
#pragma unroll
    for (int c = 0; c < C_; ++c) s[c] = 0.f;
    float wsum = 1e-5f;

    for (int i = 0; i < NSRC; ++i) {
        float vw = view_weights[((size_t)(b * NSRC + i) * H_ + h) * W_ + w];
        wsum += vw;
        const float* pr = projs + (b * NSRC + i) * 12;
        float rx = pr[0] * xf + pr[1] * yf + pr[2];
        float ry = pr[3] * xf + pr[4] * yf + pr[5];
        float rz = pr[6] * xf + pr[7] * yf + pr[8];
        float pxn = rx * dep + pr[9];
        float pyn = ry * dep + pr[10];
        float z = rz * dep + pr[11];
        bool valid = z > 0.001f;
        float zs = valid ? z : 1.f;
        float px = valid ? pxn / zs : -10000.f;
        float py = valid ? pyn / zs : -10000.f;
        float x0f = floorf(px), y0f = floorf(py);
        float x1f = x0f + 1.f, y1f = y0f + 1.f;
        float wx1 = px - x0f, wx0 = 1.f - wx1;
        float wy1 = py - y0f, wy0 = 1.f - wy1;
        bool vx0 = (x0f >= 0.f) && (x0f <= (float)(W_ - 1));
        bool vx1 = (x1f >= 0.f) && (x1f <= (float)(W_ - 1));
        bool vy0 = (y0f >= 0.f) && (y0f <= (float)(H_ - 1));
        bool vy1 = (y1f >= 0.f) && (y1f <= (float)(H_ - 1));
        int ix0 = (int)fminf(fmaxf(x0f, 0.f), (float)(W_ - 1));
        int ix1 = (int)fminf(fmaxf(x1f, 0.f), (float)(W_ - 1));
        int iy0 = (int)fminf(fmaxf(y0f, 0.f), (float)(H_ - 1));
        int iy1 = (int)fminf(fmaxf(y1f, 0.f), (float)(H_ - 1));
        float w00 = wx0 * wy0 * ((vx0 && vy0) ? vw : 0.f);
        float w10 = wx1 * wy0 * ((vx1 && vy0) ? vw : 0.f);
        float w01 = wx0 * wy1 * ((vx0 && vy1) ? vw : 0.f);
        float w11 = wx1 * wy1 * ((vx1 && vy1) ? vw : 0.f);
        const float* base = feat + (size_t)((i + 1) * B_ + b) * C_ * HW_;
        const float* q00 = base + (size_t)iy0 * W_ + ix0;
        const float* q10 = base + (size_t)iy0 * W_ + ix1;
        const float* q01 = base + (size_t)iy1 * W_ + ix0;
        const float* q11 = base + (size_t)iy1 * W_ + ix1;
#pragma unroll
        for (int c = 0; c < C_; ++c)
            s[c] += q00[(size_t)c * HW_] * w00 + q10[(size_t)c * HW_] * w10 +
                    q01[(size_t)c * HW_] * w01 + q11[(size_t)c * HW_] * w11;
    }
    float inv_wsum = 1.f / wsum;
    size_t obase = (size_t)b * C_ * DHW_ + (size_t)d * HW_ + (size_t)h * W_ + w;
    const float* refp = feat + (size_t)b * C_ * HW_ + (size_t)h * W_ + w;
    float pv = 0.f;
#pragma unroll
    for (int c = 0; c < C_; ++c) {
        float vc = refp[(size_t)c * HW_] * s[c] * inv_wsum;
        out_vol[obase + (size_t)c * DHW_] = vc;
        pv += vc * w_reg[c];
    }
    out_pv[tid] = pv + b_reg[0];
}

// ---------------------------------------------------------------------------
// K3: softmax over D (in-place on pv = prob slot), depth, vw passthrough.
// ---------------------------------------------------------------------------
__global__ __launch_bounds__(256) void finalize_kernel(
    const float* __restrict__ ds, const float* __restrict__ vw,
    float* __restrict__ out_depth, float* __restrict__ out_vw,
    float* __restrict__ pv) {
    int tid = blockIdx.x * 256 + threadIdx.x;
    if (tid >= BHW_) return;
    int w = tid % W_;
    int t2 = tid / W_;
    int h = t2 % H_;
    int b = t2 / H_;
    size_t base = (size_t)b * DHW_ + (size_t)h * W_ + w;

    float p[D_];
    float m = -1e30f;
#pragma unroll
    for (int d = 0; d < D_; ++d) {
        p[d] = pv[base + (size_t)d * HW_];
        m = fmaxf(m, p[d]);
    }
    float ssum = 0.f;
#pragma unroll
    for (int d = 0; d < D_; ++d) {
        p[d] = expf(p[d] - m);
        ssum += p[d];
    }
    float inv = 1.f / ssum;
    float dep = 0.f;
#pragma unroll
    for (int d = 0; d < D_; ++d) {
        float pr = p[d] * inv;
        pv[base + (size_t)d * HW_] = pr;
        dep += pr * ds[base + (size_t)d * HW_];
    }
    out_depth[tid] = dep;
#pragma unroll
    for (int k = 0; k < NSRC; ++k)
        out_vw[tid + k * BHW_] = vw[tid + k * BHW_];
}

// ---------------------------------------------------------------------------
extern "C" void kernel_launch(void* const* d_in, const int* in_sizes, int n_in,
                              void* d_out, int out_size, void* d_ws, size_t ws_size,
                              hipStream_t stream) {
    const float* features = (const float*)d_in[0];
    const float* pm       = (const float*)d_in[1];
    const float* dsamp    = (const float*)d_in[2];
    const float* vweights = (const float*)d_in[3];
    const float* w_reg    = (const float*)d_in[4];
    const float* b_reg    = (const float*)d_in[5];

    float* out = (float*)d_out;
    float* out_depth = out;                       // (B,H,W)      40960
    float* out_vw    = out + 40960;               // (B,4,H,W)    163840
    float* out_prob  = out + 204800;              // (B,D,H,W)    1966080 (pv staged here)
    float* out_vol   = out + 2170880;             // (B,C,D,H,W)  62914560

    float* wsf   = (float*)d_ws;
    float* projb = wsf;                            // 96 floats
    __hip_bfloat16* featT = (__hip_bfloat16*)(wsf + 128);  // 512B offset

    size_t need = 512 + (size_t)NSRC * B_ * HW_ * C_ * sizeof(__hip_bfloat16);
    bool chlast = (ws_size >= need);

    hipLaunchKernelGGL(proj_kernel, dim3(1), dim3(64), 0, stream, pm, projb);

    if (chlast) {
        hipLaunchKernelGGL(transpose_bf16_kernel, dim3(NSRC * B_ * H_, W_ / 32),
                           dim3(32, 8), 0, stream, features, featT);
        hipLaunchKernelGGL(vol_pair_kernel, dim3(NB_PAIR), dim3(256), 0, stream,
                           featT, features, dsamp, vweights, w_reg, b_reg, projb,
                           out_vol, out_prob);
    } else {
        hipLaunchKernelGGL(vol_fallback_kernel, dim3((TOTAL_BDHW + 255) / 256),
                           dim3(256), 0, stream, features, dsamp, vweights, w_reg,
                           b_reg, projb, out_vol, out_prob);
    }

    hipLaunchKernelGGL(finalize_kernel, dim3(BHW_ / 256), dim3(256), 0, stream,
                       dsamp, vweights, out_depth, out_vw, out_prob);
}

// Round 16
// 151.170 us; speedup vs baseline: 1.1906x; 1.0000x over previous
//
#include <hip/hip_runtime.h>
#include <hip/hip_bf16.h>
#include <math.h>

// Problem constants
#define V_ 5
#define B_ 2
#define C_ 32
#define D_ 48
#define H_ 128
#define W_ 160
#define NSRC 4
#define HW_ (H_ * W_)
#define DHW_ ((size_t)D_ * H_ * W_)
#define BHW_ (B_ * H_ * W_)             // 40960
#define TOTAL_BDHW (B_ * D_ * H_ * W_)  // 1966080

// d-quad grid: block = 256 thr = (16 w) x (4 c-quarters) x (4 h), FOUR d each.
// logical block id: dq innermost, then wg (10), h4 (32), b.
#define DD 4
#define DQUAD (D_ / DD)                               // 12
#define NB_QUAD (B_ * (H_ / 4) * (W_ / 16) * DQUAD)   // 7680
#define NB_QUAD8 (NB_QUAD / 8)                        // 960

typedef __attribute__((ext_vector_type(2))) float f32x2;

// ---------------------------------------------------------------------------
// K0: projection setup (8 threads, f64 internally).
// ---------------------------------------------------------------------------
__device__ __forceinline__ void combined_proj(const float* p, double* P) {
    double E[16], K[16];
    for (int i = 0; i < 16; ++i) { E[i] = (double)p[i]; K[i] = (double)p[16 + i]; }
    for (int i = 0; i < 16; ++i) P[i] = E[i];
    for (int r = 0; r < 3; ++r)
        for (int c = 0; c < 4; ++c) {
            double s = 0.0;
            for (int j = 0; j < 3; ++j) s += K[r * 4 + j] * E[j * 4 + c];
            P[r * 4 + c] = s;
        }
}

__device__ void invert4(const double* A, double* out) {
    double M[4][8];
    for (int r = 0; r < 4; ++r)
        for (int c = 0; c < 4; ++c) {
            M[r][c] = A[r * 4 + c];
            M[r][c + 4] = (r == c) ? 1.0 : 0.0;
        }
    for (int col = 0; col < 4; ++col) {
        int piv = col;
        double best = fabs(M[col][col]);
        for (int r = col + 1; r < 4; ++r) {
            double v = fabs(M[r][col]);
            if (v > best) { best = v; piv = r; }
        }
        if (piv != col)
            for (int c = 0; c < 8; ++c) {
                double t = M[col][c]; M[col][c] = M[piv][c]; M[piv][c] = t;
            }
        double s = 1.0 / M[col][col];
        for (int c = 0; c < 8; ++c) M[col][c] *= s;
        for (int r = 0; r < 4; ++r)
            if (r != col) {
                double f = M[r][col];
                if (f != 0.0)
                    for (int c = 0; c < 8; ++c) M[r][c] -= f * M[col][c];
            }
    }
    for (int r = 0; r < 4; ++r)
        for (int c = 0; c < 4; ++c) out[r * 4 + c] = M[r][c + 4];
}

__global__ void proj_kernel(const float* __restrict__ pm, float* __restrict__ out) {
    int t = threadIdx.x;
    if (t >= B_ * NSRC) return;
    int b = t / NSRC, i = t % NSRC;
    double Pref[16], Psrc[16];
    combined_proj(pm + (size_t)((b * V_ + 0) * 2) * 16, Pref);
    combined_proj(pm + (size_t)((b * V_ + (i + 1)) * 2) * 16, Psrc);
    double inv[16];
    invert4(Pref, inv);
    double M[16];
    for (int r = 0; r < 4; ++r)
        for (int c = 0; c < 4; ++c) {
            double s = 0.0;
            for (int j = 0; j < 4; ++j) s += Psrc[r * 4 + j] * inv[j * 4 + c];
            M[r * 4 + c] = s;
        }
    float* o = out + t * 12;
    o[0] = (float)M[0];  o[1] = (float)M[1];  o[2] = (float)M[2];
    o[3] = (float)M[4];  o[4] = (float)M[5];  o[5] = (float)M[6];
    o[6] = (float)M[8];  o[7] = (float)M[9];  o[8] = (float)M[10];
    o[9] = (float)M[3];  o[10] = (float)M[7]; o[11] = (float)M[11];
}

// ---------------------------------------------------------------------------
// K1: transpose + convert src views: (v=1..4, b, c, h, w) f32
//     -> channel-last bf16 (i, b, h, w, c), i = v-1.
// ---------------------------------------------------------------------------
__global__ __launch_bounds__(256) void transpose_bf16_kernel(
    const float* __restrict__ in, __hip_bfloat16* __restrict__ outT) {
    __shared__ float tile[32][33];
    int ibh = blockIdx.x;                 // (i*B + b)*H + h
    int w0 = blockIdx.y * 32;
    int h = ibh % H_;
    int ib = ibh / H_;                    // i*B + b
    int i = ib / B_, b = ib % B_;
    int tx = threadIdx.x, ty = threadIdx.y;
    const float* src = in + ((size_t)((i + 1) * B_ + b) * C_) * HW_ + (size_t)h * W_ + w0;
#pragma unroll
    for (int cs = 0; cs < 32; cs += 8)
        tile[cs + ty][tx] = src[(size_t)(cs + ty) * HW_ + tx];
    __syncthreads();
    __hip_bfloat16* dst = outT + ((size_t)ib * HW_ + (size_t)h * W_ + w0) * C_;
#pragma unroll
    for (int wv = 0; wv < 32; wv += 8)
        dst[(size_t)(wv + ty) * C_ + tx] = __float2bfloat16(tile[tx][wv + ty]);
}

// ---------------------------------------------------------------------------
// K2: sequential d-quad volume kernel (r15 structure, DD=4).
// Exact r13 per-d body in a dd in {0..3} loop: later d's gathers hit lines
// earlier d pulled into THIS CU's L1; d-invariant state (vw, wsum, ref,
// w_reg, per-view rx/ry/rz) amortized over 4 depths.
// No LDS, no barriers, no sched pinning.
// ---------------------------------------------------------------------------
__global__ __launch_bounds__(256) void vol_quad_kernel(
    const __hip_bfloat16* __restrict__ featT, const float* __restrict__ features,
    const float* __restrict__ depth_samples, const float* __restrict__ view_weights,
    const float* __restrict__ w_reg, const float* __restrict__ b_reg,
    const float* __restrict__ projs, float* __restrict__ out_vol,
    float* __restrict__ out_pv) {
    int bid = blockIdx.x;
    int lid = (bid & 7) * NB_QUAD8 + (bid >> 3);   // bijective XCD chunking
    int dq = lid % DQUAD;
    int r = lid / DQUAD;
    int wg = r % (W_ / 16);
    r /= (W_ / 16);
    int h4 = r % (H_ / 4);
    int b = r / (H_ / 4);                          // block-uniform -> SGPR
    int d0 = dq * DD;

    int tix = threadIdx.x;
    int w16 = tix & 15;
    int c4 = (tix >> 4) & 3;
    int hg = tix >> 6;
    int h = h4 * 4 + hg;
    int w = wg * 16 + w16;
    int c0 = c4 * 8;
    int hw = h * W_ + w;
    float xf = (float)w, yf = (float)h;

    // ---- d-invariant state ----
    float vwa[NSRC];
    float wsum = 1e-5f;
#pragma unroll
    for (int i = 0; i < NSRC; ++i) {
        vwa[i] = view_weights[((size_t)(b * NSRC + i)) * HW_ + hw];
        wsum += vwa[i];
    }
    float inv_wsum = __builtin_amdgcn_rcpf(wsum);   // wsum in [0.4, 4.0001]
    f32x2 iw2 = (f32x2){inv_wsum, inv_wsum};

    const float* refp = features + ((size_t)b * C_ + c0) * HW_ + hw;
    f32x2 rf2[4];
#pragma unroll
    for (int j = 0; j < 4; ++j) {
        rf2[j].x = refp[(size_t)(2 * j) * HW_];
        rf2[j].y = refp[(size_t)(2 * j + 1) * HW_];
    }
    float wrr[8];
#pragma unroll
    for (int k = 0; k < 8; ++k) wrr[k] = w_reg[c0 + k];
    float breg = b_reg[0];

    // per-view projection pieces (depend on (w,h) only)
    float rxv[NSRC], ryv[NSRC], rzv[NSRC];
#pragma unroll
    for (int i = 0; i < NSRC; ++i) {
        const float* pr = projs + (b * NSRC + i) * 12;
        rxv[i] = pr[0] * xf + pr[1] * yf + pr[2];
        ryv[i] = pr[3] * xf + pr[4] * yf + pr[5];
        rzv[i] = pr[6] * xf + pr[7] * yf + pr[8];
    }

    int pixbase = (b * D_) * HW_ + hw;             // + d*HW_
    size_t obase0 = (size_t)b * C_ * DHW_ + hw;    // + d*HW_ + c*DHW_

#pragma unroll
    for (int dd = 0; dd < DD; ++dd) {
        int d = d0 + dd;
        float dep = depth_samples[pixbase + d * HW_];

        f32x2 acc[4];
#pragma unroll
        for (int j = 0; j < 4; ++j) acc[j] = (f32x2){0.f, 0.f};

#pragma unroll
        for (int i = 0; i < NSRC; ++i) {
            float vw = vwa[i];
            const float* pr = projs + (b * NSRC + i) * 12;
            float pxn = rxv[i] * dep + pr[9];
            float pyn = ryv[i] * dep + pr[10];
            float z = rzv[i] * dep + pr[11];
            bool valid = z > 0.001f;
            float zr = __builtin_amdgcn_rcpf(valid ? z : 1.f);
            float px = valid ? pxn * zr : -10000.f;
            float py = valid ? pyn * zr : -10000.f;

            float x0f = floorf(px), y0f = floorf(py);
            float x1f = x0f + 1.f, y1f = y0f + 1.f;
            float wx1 = px - x0f, wx0 = 1.f - wx1;
            float wy1 = py - y0f, wy0 = 1.f - wy1;
            bool vx0 = (x0f >= 0.f) && (x0f <= (float)(W_ - 1));
            bool vx1 = (x1f >= 0.f) && (x1f <= (float)(W_ - 1));
            bool vy0 = (y0f >= 0.f) && (y0f <= (float)(H_ - 1));
            bool vy1 = (y1f >= 0.f) && (y1f <= (float)(H_ - 1));
            int ix0 = (int)fminf(fmaxf(x0f, 0.f), (float)(W_ - 1));
            int ix1 = (int)fminf(fmaxf(x1f, 0.f), (float)(W_ - 1));
            int iy0 = (int)fminf(fmaxf(y0f, 0.f), (float)(H_ - 1));
            int iy1 = (int)fminf(fmaxf(y1f, 0.f), (float)(H_ - 1));
            float w00 = wx0 * wy0 * ((vx0 && vy0) ? vw : 0.f);
            float w10 = wx1 * wy0 * ((vx1 && vy0) ? vw : 0.f);
            float w01 = wx0 * wy1 * ((vx0 && vy1) ? vw : 0.f);
            float w11 = wx1 * wy1 * ((vx1 && vy1) ? vw : 0.f);

            const __hip_bfloat16* base = featT + (size_t)(i * B_ + b) * HW_ * C_ + c0;
            uint4 u00 = *(const uint4*)(base + (size_t)(iy0 * W_ + ix0) * C_);
            uint4 u10 = *(const uint4*)(base + (size_t)(iy0 * W_ + ix1) * C_);
            uint4 u01 = *(const uint4*)(base + (size_t)(iy1 * W_ + ix0) * C_);
            uint4 u11 = *(const uint4*)(base + (size_t)(iy1 * W_ + ix1) * C_);

#define ACCPK(word, j, wv2)                                              \
            {                                                            \
                f32x2 tt;                                                \
                tt.x = __uint_as_float((word) << 16);                    \
                tt.y = __uint_as_float((word) & 0xffff0000u);            \
                acc[j] += tt * (wv2);                                    \
            }
#define ACCTAP(uu, wgt)                                                  \
            {                                                            \
                f32x2 wv2 = (f32x2){(wgt), (wgt)};                       \
                ACCPK((uu).x, 0, wv2)                                    \
                ACCPK((uu).y, 1, wv2)                                    \
                ACCPK((uu).z, 2, wv2)                                    \
                ACCPK((uu).w, 3, wv2)                                    \
            }
            ACCTAP(u00, w00)
            ACCTAP(u10, w10)
            ACCTAP(u01, w01)
            ACCTAP(u11, w11)
#undef ACCTAP
#undef ACCPK
        }

        size_t obase = obase0 + (size_t)d * HW_;
        f32x2 vc2[4];
#pragma unroll
        for (int j = 0; j < 4; ++j) vc2[j] = rf2[j] * acc[j] * iw2;
        float pv = 0.f;
#pragma unroll
        for (int k = 0; k < 8; ++k) {
            float vc = vc2[k >> 1][k & 1];
            __builtin_nontemporal_store(vc, &out_vol[obase + (size_t)(c0 + k) * DHW_]);
            pv += vc * wrr[k];
        }
        pv += __shfl_xor(pv, 16, 64);
        pv += __shfl_xor(pv, 32, 64);
        if (c4 == 0) out_pv[pixbase + d * HW_] = pv + breg;
    }
}

// ---------------------------------------------------------------------------
// Fallback: one-thread-per-pixel channel-first f32 kernel (no workspace).
// ---------------------------------------------------------------------------
__global__ __launch_bounds__(256) void vol_fallback_kernel(
    const float* __restrict__ feat, const float* __restrict__ depth_samples,
    const float* __restrict__ view_weights, const float* __restrict__ w_reg,
    const float* __restrict__ b_reg, const float* __restrict__ projs,
    float* __restrict__ out_vol, float* __restrict__ out_pv) {
    int tid = blockIdx.x * 256 + threadIdx.x;
    if (tid >= TOTAL_BDHW) return;
    int w = tid % W_;
    int t2 = tid / W_;
    int h = t2 % H_;
    t2 /= H_;
    int d = t2 % D_;
    int b = t2 / D_;

    float xf = (float)w, yf = (float)h;
    float dep = depth_samples[tid];
    float s[C_];
#pragma unroll
    for (int c = 0; c < C_; ++c) s[c] = 0.f;
    float wsum = 1e-5f;

    for (int i = 0; i < NSRC; ++i) {
        float vw = view_weights[((size_t)(b * NSRC + i) * H_ + h) * W_ + w];
        wsum += vw;
        const float* pr = projs + (b * NSRC + i) * 12;
        float rx = pr[0] * xf + pr[1] * yf + pr[2];
        float ry = pr[3] * xf + pr[4] * yf + pr[5];
        float rz = pr[6] * xf + pr[7] * yf + pr[8];
        float pxn = rx * dep + pr[9];
        float pyn = ry * dep + pr[10];
        float z = rz * dep + pr[11];
        bool valid = z > 0.001f;
        float zs = valid ? z : 1.f;
        float px = valid ? pxn / zs : -10000.f;
        float py = valid ? pyn / zs : -10000.f;
        float x0f = floorf(px), y0f = floorf(py);
        float x1f = x0f + 1.f, y1f = y0f + 1.f;
        float wx1 = px - x0f, wx0 = 1.f - wx1;
        float wy1 = py - y0f, wy0 = 1.f - wy1;
        bool vx0 = (x0f >= 0.f) && (x0f <= (float)(W_ - 1));
        bool vx1 = (x1f >= 0.f) && (x1f <= (float)(W_ - 1));
        bool vy0 = (y0f >= 0.f) && (y0f <= (float)(H_ - 1));
        bool vy1 = (y1f >= 0.f) && (y1f <= (float)(H_ - 1));
        int ix0 = (int)fminf(fmaxf(x0f, 0.f), (float)(W_ - 1));
        int ix1 = (int)fminf(fmaxf(x1f, 0.f), (float)(W_ - 1));
        int iy0 = (int)fminf(fmaxf(y0f, 0.f), (float)(H_ - 1));
        int iy1 = (int)fminf(fmaxf(y1f, 0.f), (float)(H_ - 1));
        float w00 = wx0 * wy0 * ((vx0 && vy0) ? vw : 0.f);
        float w10 = wx1 * wy0 * ((vx1 && vy0) ? vw : 0.f);
        float w01 = wx0 * wy1 * ((vx0 && vy1) ? vw : 0.f);
        float w11 = wx1 * wy1 * ((vx1 && vy1) ? vw : 0.f);
        const float* base = feat + (size_t)((i + 1) * B_ + b) * C_ * HW_;
        const float* q00 = base + (size_t)iy0 * W_ + ix0;
        const float* q10 = base + (size_t)iy0 * W_ + ix1;
        const float* q01 = base + (size_t)iy1 * W_ + ix0;
        const float* q11 = base + (size_t)iy1 * W_ + ix1;
#pragma unroll
        for (int c = 0; c < C_; ++c)
            s[c] += q00[(size_t)c * HW_] * w00 + q10[(size_t)c * HW_] * w10 +
                    q01[(size_t)c * HW_] * w01 + q11[(size_t)c * HW_] * w11;
    }
    float inv_wsum = 1.f / wsum;
    size_t obase = (size_t)b * C_ * DHW_ + (size_t)d * HW_ + (size_t)h * W_ + w;
    const float* refp = feat + (size_t)b * C_ * HW_ + (size_t)h * W_ + w;
    float pv = 0.f;
#pragma unroll
    for (int c = 0; c < C_; ++c) {
        float vc = refp[(size_t)c * HW_] * s[c] * inv_wsum;
        out_vol[obase + (size_t)c * DHW_] = vc;
        pv += vc * w_reg[c];
    }
    out_pv[tid] = pv + b_reg[0];
}

// ---------------------------------------------------------------------------
// K3: softmax over D (in-place on pv = prob slot), depth, vw passthrough.
// ---------------------------------------------------------------------------
__global__ __launch_bounds__(256) void finalize_kernel(
    const float* __restrict__ ds, const float* __restrict__ vw,
    float* __restrict__ out_depth, float* __restrict__ out_vw,
    float* __restrict__ pv) {
    int tid = blockIdx.x * 256 + threadIdx.x;
    if (tid >= BHW_) return;
    int w = tid % W_;
    int t2 = tid / W_;
    int h = t2 % H_;
    int b = t2 / H_;
    size_t base = (size_t)b * DHW_ + (size_t)h * W_ + w;

    float p[D_];
    float m = -1e30f;
#pragma unroll
    for (int d = 0; d < D_; ++d) {
        p[d] = pv[base + (size_t)d * HW_];
        m = fmaxf(m, p[d]);
    }
    float ssum = 0.f;
#pragma unroll
    for (int d = 0; d < D_; ++d) {
        p[d] = expf(p[d] - m);
        ssum += p[d];
    }
    float inv = 1.f / ssum;
    float dep = 0.f;
#pragma unroll
    for (int d = 0; d < D_; ++d) {
        float pr = p[d] * inv;
        pv[base + (size_t)d * HW_] = pr;
        dep += pr * ds[base + (size_t)d * HW_];
    }
    out_depth[tid] = dep;
#pragma unroll
    for (int k = 0; k < NSRC; ++k)
        out_vw[tid + k * BHW_] = vw[tid + k * BHW_];
}

// ---------------------------------------------------------------------------
extern "C" void kernel_launch(void* const* d_in, const int* in_sizes, int n_in,
                              void* d_out, int out_size, void* d_ws, size_t ws_size,
                              hipStream_t stream) {
    const float* features = (const float*)d_in[0];
    const float* pm       = (const float*)d_in[1];
    const float* dsamp    = (const float*)d_in[2];
    const float* vweights = (const float*)d_in[3];
    const float* w_reg    = (const float*)d_in[4];
    const float* b_reg    = (const float*)d_in[5];

    float* out = (float*)d_out;
    float* out_depth = out;                       // (B,H,W)      40960
    float* out_vw    = out + 40960;               // (B,4,H,W)    163840
    float* out_prob  = out + 204800;              // (B,D,H,W)    1966080 (pv staged here)
    float* out_vol   = out + 2170880;             // (B,C,D,H,W)  62914560

    float* wsf   = (float*)d_ws;
    float* projb = wsf;                            // 96 floats
    __hip_bfloat16* featT = (__hip_bfloat16*)(wsf + 128);  // 512B offset

    size_t need = 512 + (size_t)NSRC * B_ * HW_ * C_ * sizeof(__hip_bfloat16);
    bool chlast = (ws_size >= need);

    hipLaunchKernelGGL(proj_kernel, dim3(1), dim3(64), 0, stream, pm, projb);

    if (chlast) {
        hipLaunchKernelGGL(transpose_bf16_kernel, dim3(NSRC * B_ * H_, W_ / 32),
                           dim3(32, 8), 0, stream, features, featT);
        hipLaunchKernelGGL(vol_quad_kernel, dim3(NB_QUAD), dim3(256), 0, stream,
                           featT, features, dsamp, vweights, w_reg, b_reg, projb,
                           out_vol, out_prob);
    } else {
        hipLaunchKernelGGL(vol_fallback_kernel, dim3((TOTAL_BDHW + 255) / 256),
                           dim3(256), 0, stream, features, dsamp, vweights, w_reg,
                           b_reg, projb, out_vol, out_prob);
    }

    hipLaunchKernelGGL(finalize_kernel, dim3(BHW_ / 256), dim3(256), 0, stream,
                       dsamp, vweights, out_depth, out_vw, out_prob);
}